// Round 6
// baseline (2389.422 us; speedup 1.0000x reference)
//
#include <hip/hip_runtime.h>
#include <hip/hip_bf16.h>

#define SQ 1024
#define DM 768
#define NH 12
#define NL 6
#define NV 32000
#define KDH 64
#define FFD 3072

using bf16 = __hip_bfloat16;
typedef __attribute__((ext_vector_type(4))) float f32x4;
typedef __attribute__((ext_vector_type(8))) short bf16x8;

// ---------------- diagnostic fill (fp32 out) ----------------
__global__ void fill_kernel(float* __restrict__ out, long n, float val) {
  const long stride = (long)gridDim.x * blockDim.x;
  for (long i = (long)blockIdx.x * blockDim.x + threadIdx.x; i < n; i += stride)
    out[i] = val;
}

// async global->LDS, 16 bytes per lane
__device__ __forceinline__ void gload16(const void* g, void* l) {
  __builtin_amdgcn_global_load_lds(
      (const __attribute__((address_space(1))) unsigned int*)g,
      (__attribute__((address_space(3))) unsigned int*)l, 16, 0, 0);
}

// ---------------- MFMA GEMM, both operands bf16 k-contiguous ----------------
// C[z; m, n] = A[z; m, :] * BT[z; n, :] + bias[z; n]
// A: [M, lda] bf16 row-major; BT: [N, ldbt] bf16 row-major (= B^T, k-contig).
// 128x128 tile, BK=32, double-buffered global_load_lds staging (2-phase,
// counted-overlap: next tile in flight during MFMA), 16B-slot XOR swizzle,
// bijective XCD-aware block swizzle (m204).
// C index = z*sCz + (m>>10)*sCb + (m&1023)*sCs + n*sCn   (fp32 or bf16 out)
// Requires: M%128==0, N%128==0, K%32==0.
template<bool OUT_BF16, bool RELU>
__global__ __launch_bounds__(256) void gemm_bt(
    int M, int N, int K,
    const bf16* __restrict__ Ap, long sAz, int lda,
    const bf16* __restrict__ Bp, long sBz, int ldbt,
    const float* __restrict__ biasp, int sBiasZ,
    void* __restrict__ Cp, long sCz, long sCb, long sCs, long sCn)
{
  __shared__ __align__(16) char lds[32768];   // 2 x (8KB A + 8KB B)

  const int tid = threadIdx.x;

  // ---- bijective XCD-aware block swizzle (T1, m204): XCD c gets a
  // contiguous chunk of x-major tiles -> same-B-panel tiles share an L2 ----
  const int gx = gridDim.x, gy = gridDim.y;
  const int nwg = gx * gy * (int)gridDim.z;
  int flat = ((int)blockIdx.z * gy + (int)blockIdx.y) * gx + (int)blockIdx.x;
  {
    const int q = nwg >> 3, r = nwg & 7;
    const int xcd = flat & 7, loc = flat >> 3;
    flat = (xcd < r ? xcd * (q + 1) : r * (q + 1) + (xcd - r) * q) + loc;
  }
  const int bx  = flat % gx;
  const int byz = flat / gx;
  const int m0 = bx * 128;
  const int n0 = (byz % gy) * 128;
  const int z  = byz / gy;

  const int lane = tid & 63;
  const int wid  = tid >> 6;
  const int wm = (wid >> 1) * 64;
  const int wn = (wid & 1) * 64;

  const int srow  = tid >> 2;    // staging row (0..63), +64 for p=1
  const int sslot = tid & 3;     // 16B slot in 64B row

  const bf16* Ab = Ap + (long)z * sAz;
  const bf16* Bb = Bp + (long)z * sBz;

  char* const A0 = lds;
  char* const B0 = lds + 8192;
  char* const A1 = lds + 16384;
  char* const B1 = lds + 24576;

  f32x4 acc[4][4] = {};

  // stage one 128x32 A-tile + 128x32 B-tile into (Asb,Bsb); global slot
  // pre-swizzled so the LDS dest stays linear (rule #21)
  auto stage = [&](int kt, char* Asb, char* Bsb) {
#pragma unroll
    for (int p = 0; p < 2; ++p) {
      const int r_ = srow + p * 64;
      const char* ga = (const char*)(Ab + (long)(m0 + r_) * lda + kt)
                     + ((sslot ^ (r_ & 3)) << 4);
      gload16(ga, Asb + (tid + p * 256) * 16);
    }
#pragma unroll
    for (int p = 0; p < 2; ++p) {
      const int r_ = srow + p * 64;
      const char* gb = (const char*)(Bb + (long)(n0 + r_) * ldbt + kt)
                     + ((sslot ^ (r_ & 3)) << 4);
      gload16(gb, Bsb + (tid + p * 256) * 16);
    }
  };

  auto compute = [&](const char* Asb, const char* Bsb) {
    const int fr = lane & 15;
    const int kq = lane >> 4;
    bf16x8 af[4], bfr[4];
#pragma unroll
    for (int m = 0; m < 4; ++m) {
      const int R = wm + m * 16 + fr;
      af[m] = *(const bf16x8*)(Asb + R * 64 + ((kq ^ (R & 3)) << 4));
    }
#pragma unroll
    for (int n = 0; n < 4; ++n) {
      const int R = wn + n * 16 + fr;
      bfr[n] = *(const bf16x8*)(Bsb + R * 64 + ((kq ^ (R & 3)) << 4));
    }
#pragma unroll
    for (int m = 0; m < 4; ++m)
#pragma unroll
      for (int n = 0; n < 4; ++n)
        acc[m][n] = __builtin_amdgcn_mfma_f32_16x16x32_bf16(af[m], bfr[n], acc[m][n], 0, 0, 0);
  };

  // prologue: stage tile 0, drain, sync
  stage(0, A0, B0);
  asm volatile("s_waitcnt vmcnt(0)" ::: "memory");
  __builtin_amdgcn_s_barrier();

  int cur = 0;
  for (int kt = 0; kt < K; kt += 32) {
    // issue next-tile loads first: they fly during this tile's MFMA
    if (kt + 32 < K) {
      if (cur == 0) stage(kt + 32, A1, B1);
      else          stage(kt + 32, A0, B0);
    }
    if (cur == 0) compute(A0, B0);
    else          compute(A1, B1);
    // next tile ready + all waves done reading cur before it's overwritten
    asm volatile("s_waitcnt vmcnt(0)" ::: "memory");
    __builtin_amdgcn_s_barrier();
    cur ^= 1;
  }

  // epilogue: C/D layout col=lane&15, row=(lane>>4)*4+reg
  const int rg = (lane >> 4) * 4;
  const int cl = lane & 15;
#pragma unroll
  for (int n = 0; n < 4; ++n) {
    const int gcol = n0 + wn + n * 16 + cl;
    float bias = 0.f;
    if (biasp) bias = biasp[(long)z * sBiasZ + gcol];
#pragma unroll
    for (int m = 0; m < 4; ++m) {
#pragma unroll
      for (int rr = 0; rr < 4; ++rr) {
        const int grow = m0 + wm + m * 16 + rg + rr;
        float v = acc[m][n][rr] + bias;
        if (RELU) v = fmaxf(v, 0.f);
        const long ci = (long)z * sCz + (long)(grow >> 10) * sCb
                      + (long)(grow & 1023) * sCs + (long)gcol * sCn;
        if (OUT_BF16) ((bf16*)Cp)[ci] = __float2bfloat16(v);
        else          ((float*)Cp)[ci] = v;
      }
    }
  }
}

// ---------------- fp32 [Kd,Nd] -> bf16 [Nd,Kd] transpose ----------------
// grid: (Nd/64, Kd/64, Z)
__global__ __launch_bounds__(256) void transpose_kernel(
    const float* __restrict__ in, long sInZ, int ldin,
    bf16* __restrict__ out, long sOutZ, int ldout)
{
  __shared__ float t[64][65];
  const int tid = threadIdx.x;
  const int n0 = blockIdx.x * 64, k0 = blockIdx.y * 64;
  const float* ip = in + (long)blockIdx.z * sInZ;
  bf16* op = out + (long)blockIdx.z * sOutZ;
  const int cx = (tid & 15) * 4, ry = tid >> 4;
#pragma unroll
  for (int p = 0; p < 4; ++p) {
    const int k = ry + p * 16;
    const float4 v = *(const float4*)(ip + (long)(k0 + k) * ldin + n0 + cx);
    t[k][cx] = v.x; t[k][cx + 1] = v.y; t[k][cx + 2] = v.z; t[k][cx + 3] = v.w;
  }
  __syncthreads();
#pragma unroll
  for (int p = 0; p < 4; ++p) {
    const int n = ry + p * 16;
    ushort4 o;
    o.x = __builtin_bit_cast(ushort, __float2bfloat16(t[cx + 0][n]));
    o.y = __builtin_bit_cast(ushort, __float2bfloat16(t[cx + 1][n]));
    o.z = __builtin_bit_cast(ushort, __float2bfloat16(t[cx + 2][n]));
    o.w = __builtin_bit_cast(ushort, __float2bfloat16(t[cx + 3][n]));
    *(ushort4*)(op + (long)(n0 + n) * ldout + k0 + cx) = o;
  }
}

// ---------------- stacked Q/K bias: [H][128] fp32 ----------------
__global__ void biasqk_kernel(const float* __restrict__ bq, const float* __restrict__ bk,
                              float* __restrict__ out) {
  const int i = blockIdx.x * 256 + threadIdx.x;
  if (i < NH * 128) {
    const int h = i >> 7, n = i & 127;
    out[i] = (n < 64) ? bq[h * 64 + n] : bk[h * 64 + n - 64];
  }
}

// ---------------- embedding + sinusoidal PE -> x fp32 + xb bf16 ----------------
__global__ __launch_bounds__(256) void embed_kernel(
    const int* __restrict__ tok, const float* __restrict__ emb,
    float* __restrict__ x, bf16* __restrict__ xb)
{
  const int gid = blockIdx.x * 256 + threadIdx.x;
  const int row = gid / (DM / 4);
  const int dc  = (gid % (DM / 4)) * 4;
  const int t = tok[row];
  const int s = row & (SQ - 1);
#pragma unroll
  for (int j = 0; j < 4; ++j) {
    const int d = dc + j;
    const float e = emb[(long)t * DM + d];
    const float div = expf(-(float)(d & ~1) * (9.210340371976184f / (float)DM));
    const float ang = (float)s * div;
    const float pe = (d & 1) ? cosf(ang) : sinf(ang);
    const float v = e + pe;
    x[(long)row * DM + d] = v;
    xb[(long)row * DM + d] = __float2bfloat16(v);
  }
}

// ---------------- masked softmax, in place over bf16 scores ----------------
__global__ __launch_bounds__(256) void softmax_kernel(
    bf16* __restrict__ P, const int* __restrict__ tok)
{
  const int row = blockIdx.x;          // (b*H+h)*S + s
  const int s = row & (SQ - 1);
  const int z = row >> 10;
  const int b = z / NH;
  bf16* sp = P + (long)row * SQ;
  const int* tb = tok + b * SQ;
  const int tid = threadIdx.x;
  const int t0 = tid * 4;

  if (tb[s] == 0) {                    // pad query: uniform attention
    const bf16 u = __float2bfloat16(1.0f / (float)SQ);
    sp[t0] = u; sp[t0 + 1] = u; sp[t0 + 2] = u; sp[t0 + 3] = u;
    return;
  }
  uint2 raw = *(const uint2*)(sp + t0);
  int4 tv = *(const int4*)(tb + t0);
  const bf16* rh = (const bf16*)&raw;
  const int tvv[4] = {tv.x, tv.y, tv.z, tv.w};
  float val[4];
  float vmax = -1e30f;
#pragma unroll
  for (int j = 0; j < 4; ++j) {
    const int t = t0 + j;
    const bool valid = (t <= s) && (tvv[j] != 0);
    val[j] = valid ? __bfloat162float(rh[j]) * 0.125f : -1e30f;
    vmax = fmaxf(vmax, val[j]);
  }
  __shared__ float red[4];
  const int lane = tid & 63, wid = tid >> 6;
  float w = vmax;
#pragma unroll
  for (int o = 32; o >= 1; o >>= 1) w = fmaxf(w, __shfl_xor(w, o));
  if (lane == 0) red[wid] = w;
  __syncthreads();
  const float Mx = fmaxf(fmaxf(red[0], red[1]), fmaxf(red[2], red[3]));
  __syncthreads();
  float e[4]; float lsum = 0.f;
#pragma unroll
  for (int j = 0; j < 4; ++j) {
    e[j] = (val[j] > -1e29f) ? expf(val[j] - Mx) : 0.f;
    lsum += e[j];
  }
  w = lsum;
#pragma unroll
  for (int o = 32; o >= 1; o >>= 1) w += __shfl_xor(w, o);
  if (lane == 0) red[wid] = w;
  __syncthreads();
  const float inv = 1.0f / (red[0] + red[1] + red[2] + red[3]);
#pragma unroll
  for (int j = 0; j < 4; ++j) sp[t0 + j] = __float2bfloat16(e[j] * inv);
}

// ---------------- residual (+head-mean) + LayerNorm, x & xb updated ----------------
template<int MODE>
__global__ __launch_bounds__(256) void ln_kernel(
    float* __restrict__ x, bf16* __restrict__ xb,
    const float* __restrict__ tmp, const bf16* __restrict__ heads,
    const float* __restrict__ g, const float* __restrict__ be)
{
  const int r = blockIdx.x;            // b*S + s
  const int b = r >> 10;
  const int s = r & (SQ - 1);
  const int tid = threadIdx.x;
  float vals[3];
  float sum = 0.f, sq = 0.f;
#pragma unroll
  for (int i = 0; i < 3; ++i) {
    const int d = tid + i * 256;
    const float a = x[(long)r * DM + d];
    float t;
    if (MODE == 0) {
      t = tmp[(long)r * DM + d];
    } else {
      float hs = 0.f;
#pragma unroll
      for (int h = 0; h < NH; ++h)
        hs += __bfloat162float(heads[((long)(b * NH + h) * SQ + s) * DM + d]);
      t = hs * (1.0f / (float)NH);
    }
    const float vv = a + t;
    vals[i] = vv;
    sum += vv; sq += vv * vv;
  }
  __shared__ float rs[4], rq[4];
  const int lane = tid & 63, wid = tid >> 6;
  float s1 = sum, s2 = sq;
#pragma unroll
  for (int o = 32; o >= 1; o >>= 1) { s1 += __shfl_xor(s1, o); s2 += __shfl_xor(s2, o); }
  if (lane == 0) { rs[wid] = s1; rq[wid] = s2; }
  __syncthreads();
  const float S1 = rs[0] + rs[1] + rs[2] + rs[3];
  const float S2 = rq[0] + rq[1] + rq[2] + rq[3];
  const float mean = S1 * (1.0f / (float)DM);
  const float var  = S2 * (1.0f / (float)DM) - mean * mean;
  const float rstd = rsqrtf(var + 1e-5f);
#pragma unroll
  for (int i = 0; i < 3; ++i) {
    const int d = tid + i * 256;
    const float o = (vals[i] - mean) * rstd * g[d] + be[d];
    x[(long)r * DM + d] = o;
    xb[(long)r * DM + d] = __float2bfloat16(o);
  }
}

extern "C" void kernel_launch(void* const* d_in, const int* in_sizes, int n_in,
                              void* d_out, int out_size, void* d_ws, size_t ws_size,
                              hipStream_t stream) {
  // ---- harness-contract tripwires ----
  const int expect_sizes[18] = {
    2048, 24576000, 3538944, 4608, 3538944, 4608, 42467328, 55296,
    4608, 4608, 4608, 4608, 14155776, 18432, 14155776, 4608, 24576000, 32000
  };
  bool sizes_ok = (n_in == 18);
  if (sizes_ok)
    for (int i = 0; i < 18; ++i) sizes_ok = sizes_ok && (in_sizes[i] == expect_sizes[i]);
  if (!sizes_ok) {
    fill_kernel<<<2048, 256, 0, stream>>>((float*)d_out, (long)out_size, 1000.0f);
    return;
  }
  if (out_size != 65536000) {
    fill_kernel<<<2048, 256, 0, stream>>>((float*)d_out, (long)out_size, 3000.0f);
    return;
  }
  if (ws_size < 158081024ull) {
    fill_kernel<<<2048, 256, 0, stream>>>((float*)d_out, (long)out_size, 2000.0f);
    return;
  }

  const int*   tok  = (const int*)d_in[0];
  const float* emb  = (const float*)d_in[1];
  const float* Wq   = (const float*)d_in[2];
  const float* bq   = (const float*)d_in[3];
  const float* Wk   = (const float*)d_in[4];
  const float* bk   = (const float*)d_in[5];
  const float* Wv   = (const float*)d_in[6];
  const float* bv   = (const float*)d_in[7];
  const float* g1   = (const float*)d_in[8];
  const float* be1  = (const float*)d_in[9];
  const float* g2   = (const float*)d_in[10];
  const float* be2  = (const float*)d_in[11];
  const float* W1   = (const float*)d_in[12];
  const float* b1   = (const float*)d_in[13];
  const float* W2   = (const float*)d_in[14];
  const float* b2   = (const float*)d_in[15];
  const float* Wout = (const float*)d_in[16];
  const float* bout = (const float*)d_in[17];

  char* ws = (char*)d_ws;
  float* x      = (float*)(ws + 0);            // fp32 [B,S,D]        6,291,456
  bf16*  xb     = (bf16*) (ws + 6291456);      // bf16 [B,S,D]        3,145,728
  bf16*  qk     = (bf16*) (ws + 9437184);      // bf16 [B,H,S,128]    6,291,456 (union w/ tmp)
  float* tmp    = (float*)(ws + 9437184);      // fp32 [B,S,D]        (FF phase)
  bf16*  vT     = (bf16*) (ws + 15728640);     // bf16 [B,H,D,S]     37,748,736
  bf16*  P      = (bf16*) (ws + 53477376);     // bf16 [B,H,S,S]     50,331,648 (union w/ ff, woutT)
  bf16*  ff     = (bf16*) (ws + 53477376);     // bf16 [B,S,FF]      12,582,912
  bf16*  woutT  = (bf16*) (ws + 53477376);     // bf16 [V,D]         49,152,000
  bf16*  heads  = (bf16*) (ws + 103809024);    // bf16 [B,H,S,D]     37,748,736
  bf16*  wqkT   = (bf16*) (ws + 141557760);    // bf16 [H,128,D]      2,359,296
  bf16*  wvT    = (bf16*) (ws + 143917056);    // bf16 [H,D,D]       14,155,776
  bf16*  w1T    = (bf16*) (ws + 141557760);    // bf16 [FF,D]         4,718,592 (FF phase)
  bf16*  w2T    = (bf16*) (ws + 146276352);    // bf16 [D,FF]         4,718,592
  float* biasqk = (float*)(ws + 158072832);    // fp32 [H,128]            6,144

  embed_kernel<<<dim3((2 * SQ * DM / 4) / 256), 256, 0, stream>>>(tok, emb, x, xb);

  for (int l = 0; l < NL; ++l) {
    // --- weight prep (attention) ---
    transpose_kernel<<<dim3(1, 12, NH), 256, 0, stream>>>(      // Wq[l,h]: [768,64] -> rows 0..63
        Wq + (long)l * NH * DM * KDH, (long)DM * KDH, KDH,
        wqkT, 128 * DM, DM);
    transpose_kernel<<<dim3(1, 12, NH), 256, 0, stream>>>(      // Wk[l,h] -> rows 64..127
        Wk + (long)l * NH * DM * KDH, (long)DM * KDH, KDH,
        wqkT + 64 * DM, 128 * DM, DM);
    transpose_kernel<<<dim3(12, 12, NH), 256, 0, stream>>>(     // Wv[l,h]: [768,768] -> T
        Wv + (long)l * NH * DM * DM, (long)DM * DM, DM,
        wvT, (long)DM * DM, DM);
    biasqk_kernel<<<6, 256, 0, stream>>>(bq + l * NH * KDH, bk + l * NH * KDH, biasqk);

    // --- fused Q|K projection: qk[b,h,s,0:64]=Q, [64:128]=K ---
    gemm_bt<true, false><<<dim3(16, 1, NH), 256, 0, stream>>>(
        2048, 128, DM, xb, 0, DM, wqkT, (long)128 * DM, DM,
        biasqk, 128,
        qk, (long)SQ * 128, (long)NH * SQ * 128, 128, 1);
    // --- V projection, written TRANSPOSED: vT[b,h,e,s] ---
    gemm_bt<true, false><<<dim3(16, 6, NH), 256, 0, stream>>>(
        2048, DM, DM, xb, 0, DM, wvT, (long)DM * DM, DM,
        bv + (long)l * NH * DM, DM,
        vT, (long)DM * SQ, (long)NH * DM * SQ, 1, SQ);
    // --- scores = Q @ K^T -> P ---
    gemm_bt<true, false><<<dim3(8, 8, 2 * NH), 256, 0, stream>>>(
        SQ, SQ, KDH, qk, (long)SQ * 128, 128, qk + 64, (long)SQ * 128, 128,
        (const float*)nullptr, 0,
        P, (long)SQ * SQ, 0, SQ, 1);
    softmax_kernel<<<dim3(2 * NH * SQ), 256, 0, stream>>>(P, tok);
    // --- heads = P @ V ---
    gemm_bt<true, false><<<dim3(8, 6, 2 * NH), 256, 0, stream>>>(
        SQ, DM, SQ, P, (long)SQ * SQ, SQ, vT, (long)DM * SQ, SQ,
        (const float*)nullptr, 0,
        heads, (long)SQ * DM, 0, DM, 1);
    // --- x = LN(x + mean_h(heads)) ---
    ln_kernel<1><<<dim3(2048), 256, 0, stream>>>(x, xb, nullptr, heads,
                                                 g1 + l * DM, be1 + l * DM);
    // --- weight prep (FF) ---
    transpose_kernel<<<dim3(48, 12, 1), 256, 0, stream>>>(      // W1[l]: [768,3072] -> [3072,768]
        W1 + (long)l * DM * FFD, 0, FFD, w1T, 0, DM);
    transpose_kernel<<<dim3(12, 48, 1), 256, 0, stream>>>(      // W2[l]: [3072,768] -> [768,3072]
        W2 + (long)l * FFD * DM, 0, DM, w2T, 0, FFD);
    // --- FF1: relu(x @ W1 + b1) -> ff ---
    gemm_bt<true, true><<<dim3(16, 24, 1), 256, 0, stream>>>(
        2048, FFD, DM, xb, 0, DM, w1T, 0, DM,
        b1 + (long)l * FFD, 0,
        ff, 0, (long)SQ * FFD, FFD, 1);
    // --- FF2: ff @ W2 + b2 -> tmp fp32 ---
    gemm_bt<false, false><<<dim3(16, 6, 1), 256, 0, stream>>>(
        2048, DM, FFD, ff, 0, FFD, w2T, 0, FFD,
        b2 + (long)l * DM, 0,
        tmp, 0, (long)SQ * DM, DM, 1);
    // --- x = LN(x + tmp) ---
    ln_kernel<0><<<dim3(2048), 256, 0, stream>>>(x, xb, tmp, nullptr,
                                                 g2 + l * DM, be2 + l * DM);
  }
  // --- Wout transpose (P region is dead now) + logits -> d_out fp32 ---
  transpose_kernel<<<dim3(500, 12, 1), 256, 0, stream>>>(Wout, 0, NV, woutT, 0, DM);
  gemm_bt<false, false><<<dim3(16, 250, 1), 256, 0, stream>>>(
      2048, NV, DM, xb, 0, DM, woutT, 0, DM,
      bout, 0,
      d_out, 0, (long)SQ * NV, NV, 1);
}

// Round 7
// 2091.607 us; speedup vs baseline: 1.1424x; 1.1424x over previous
//
#include <hip/hip_runtime.h>
#include <hip/hip_bf16.h>

#define SQ 1024
#define DM 768
#define NH 12
#define NL 6
#define NV 32000
#define KDH 64
#define FFD 3072

using bf16 = __hip_bfloat16;
typedef __attribute__((ext_vector_type(4))) float f32x4;
typedef __attribute__((ext_vector_type(8))) short bf16x8;

// ---------------- diagnostic fill (fp32 out) ----------------
__global__ void fill_kernel(float* __restrict__ out, long n, float val) {
  const long stride = (long)gridDim.x * blockDim.x;
  for (long i = (long)blockIdx.x * blockDim.x + threadIdx.x; i < n; i += stride)
    out[i] = val;
}

// async global->LDS, 16 bytes per lane
__device__ __forceinline__ void gload16(const void* g, void* l) {
  __builtin_amdgcn_global_load_lds(
      (const __attribute__((address_space(1))) unsigned int*)g,
      (__attribute__((address_space(3))) unsigned int*)l, 16, 0, 0);
}

// ---------------- MFMA GEMM, both operands bf16 k-contiguous ----------------
// C[z; m, n] = A[z; m, :] * BT[z; n, :] + bias[z; n]
// A: [M, lda] bf16 row-major; BT: [N, ldbt] bf16 row-major (= B^T, k-contig).
// 128x128 tile, BK=32, single-buffer global_load_lds staging (2 barriers/iter;
// round-6 showed dbuf costs occupancy > it saves latency), 16B-slot XOR
// swizzle, bijective XCD-aware block swizzle (T1/m204 — kept: FETCH 201->126MB).
// K-loop address math fully hoisted (pointer increments, K-invariant frag addrs).
// C index = z*sCz + (m>>10)*sCb + (m&1023)*sCs + n*sCn   (fp32 or bf16 out)
// Requires: M%128==0, N%128==0, K%32==0, grid size % 8 == 0.
template<bool OUT_BF16, bool RELU>
__global__ __launch_bounds__(256) void gemm_bt(
    int M, int N, int K,
    const bf16* __restrict__ Ap, long sAz, int lda,
    const bf16* __restrict__ Bp, long sBz, int ldbt,
    const float* __restrict__ biasp, int sBiasZ,
    void* __restrict__ Cp, long sCz, long sCb, long sCs, long sCn)
{
  __shared__ __align__(16) char lds[16384];
  char* const As = lds;          // [128 rows][64 B] linear (gload_lds dest)
  char* const Bs = lds + 8192;

  const int tid = threadIdx.x;

  // ---- bijective XCD-aware block swizzle: XCD c gets a contiguous chunk of
  // x-major tiles -> same-B-panel tiles share one XCD's L2 ----
  const int gx = gridDim.x, gy = gridDim.y;
  const int nwg = gx * gy * (int)gridDim.z;
  int flat = ((int)blockIdx.z * gy + (int)blockIdx.y) * gx + (int)blockIdx.x;
  {
    const int q = nwg >> 3, r = nwg & 7;
    const int xcd = flat & 7, loc = flat >> 3;
    flat = (xcd < r ? xcd * (q + 1) : r * (q + 1) + (xcd - r) * q) + loc;
  }
  const int bx  = flat % gx;
  const int byz = flat / gx;
  const int m0 = bx * 128;
  const int n0 = (byz % gy) * 128;
  const int z  = byz / gy;

  const int lane = tid & 63;
  const int wid  = tid >> 6;
  const int wm = (wid >> 1) * 64;
  const int wn = (wid & 1) * 64;

  const int srow  = tid >> 2;    // staging row (0..63), +64 for second half
  const int sslot = tid & 3;     // 16B slot in 64B row
  const int xorb  = (sslot ^ (srow & 3)) << 4;   // (srow+64)&3 == srow&3

  // hoisted stage pointers: advance 64 B (32 bf16) per K-iter
  const char* gA0 = (const char*)(Ap + (long)z * sAz + (long)(m0 + srow) * lda) + xorb;
  const char* gA1 = (const char*)(Ap + (long)z * sAz + (long)(m0 + srow + 64) * lda) + xorb;
  const char* gB0 = (const char*)(Bp + (long)z * sBz + (long)(n0 + srow) * ldbt) + xorb;
  const char* gB1 = (const char*)(Bp + (long)z * sBz + (long)(n0 + srow + 64) * ldbt) + xorb;
  char* const dA0 = As + tid * 16;
  char* const dA1 = As + (tid + 256) * 16;
  char* const dB0 = Bs + tid * 16;
  char* const dB1 = Bs + (tid + 256) * 16;

  // K-invariant fragment LDS addresses (swizzled read)
  const int fr = lane & 15;
  const int kq = lane >> 4;
  const char* fA[4];
  const char* fB[4];
#pragma unroll
  for (int m = 0; m < 4; ++m) {
    const int R = wm + m * 16 + fr;
    fA[m] = As + R * 64 + ((kq ^ (R & 3)) << 4);
  }
#pragma unroll
  for (int n = 0; n < 4; ++n) {
    const int R = wn + n * 16 + fr;
    fB[n] = Bs + R * 64 + ((kq ^ (R & 3)) << 4);
  }

  f32x4 acc[4][4] = {};

  for (int kt = 0; kt < K; kt += 32) {
    __syncthreads();                       // prev iter's frag reads done
    gload16(gA0, dA0); gload16(gA1, dA1);
    gload16(gB0, dB0); gload16(gB1, dB1);
    gA0 += 64; gA1 += 64; gB0 += 64; gB1 += 64;
    __syncthreads();                       // drains vmcnt -> tile resident
    bf16x8 af[4], bfr[4];
#pragma unroll
    for (int m = 0; m < 4; ++m) af[m] = *(const bf16x8*)fA[m];
#pragma unroll
    for (int n = 0; n < 4; ++n) bfr[n] = *(const bf16x8*)fB[n];
#pragma unroll
    for (int m = 0; m < 4; ++m)
#pragma unroll
      for (int n = 0; n < 4; ++n)
        acc[m][n] = __builtin_amdgcn_mfma_f32_16x16x32_bf16(af[m], bfr[n], acc[m][n], 0, 0, 0);
  }

  // epilogue: C/D layout col=lane&15, row=(lane>>4)*4+reg
  const int rg = (lane >> 4) * 4;
  const int cl = lane & 15;
#pragma unroll
  for (int n = 0; n < 4; ++n) {
    const int gcol = n0 + wn + n * 16 + cl;
    float bias = 0.f;
    if (biasp) bias = biasp[(long)z * sBiasZ + gcol];
    if (OUT_BF16 && sCs == 1) {
      // transposed write (vT): 4 consecutive rows -> one ushort4 store
#pragma unroll
      for (int m = 0; m < 4; ++m) {
        const int grow = m0 + wm + m * 16 + rg;
        const long ci = (long)z * sCz + (long)(grow >> 10) * sCb
                      + (long)(grow & 1023) + (long)gcol * sCn;
        ushort4 pk;
        float v0 = acc[m][n][0] + bias, v1 = acc[m][n][1] + bias;
        float v2 = acc[m][n][2] + bias, v3 = acc[m][n][3] + bias;
        if (RELU) { v0 = fmaxf(v0, 0.f); v1 = fmaxf(v1, 0.f);
                    v2 = fmaxf(v2, 0.f); v3 = fmaxf(v3, 0.f); }
        pk.x = __builtin_bit_cast(ushort, __float2bfloat16(v0));
        pk.y = __builtin_bit_cast(ushort, __float2bfloat16(v1));
        pk.z = __builtin_bit_cast(ushort, __float2bfloat16(v2));
        pk.w = __builtin_bit_cast(ushort, __float2bfloat16(v3));
        *(ushort4*)((bf16*)Cp + ci) = pk;
      }
    } else {
#pragma unroll
      for (int m = 0; m < 4; ++m) {
#pragma unroll
        for (int rr = 0; rr < 4; ++rr) {
          const int grow = m0 + wm + m * 16 + rg + rr;
          float v = acc[m][n][rr] + bias;
          if (RELU) v = fmaxf(v, 0.f);
          const long ci = (long)z * sCz + (long)(grow >> 10) * sCb
                        + (long)(grow & 1023) * sCs + (long)gcol * sCn;
          if (OUT_BF16) ((bf16*)Cp)[ci] = __float2bfloat16(v);
          else          ((float*)Cp)[ci] = v;
        }
      }
    }
  }
}

// ---------------- fp32 [Kd,Nd] -> bf16 [Nd,Kd] transpose ----------------
// grid: (Nd/64, Kd/64, Z)
__global__ __launch_bounds__(256) void transpose_kernel(
    const float* __restrict__ in, long sInZ, int ldin,
    bf16* __restrict__ out, long sOutZ, int ldout)
{
  __shared__ float t[64][65];
  const int tid = threadIdx.x;
  const int n0 = blockIdx.x * 64, k0 = blockIdx.y * 64;
  const float* ip = in + (long)blockIdx.z * sInZ;
  bf16* op = out + (long)blockIdx.z * sOutZ;
  const int cx = (tid & 15) * 4, ry = tid >> 4;
#pragma unroll
  for (int p = 0; p < 4; ++p) {
    const int k = ry + p * 16;
    const float4 v = *(const float4*)(ip + (long)(k0 + k) * ldin + n0 + cx);
    t[k][cx] = v.x; t[k][cx + 1] = v.y; t[k][cx + 2] = v.z; t[k][cx + 3] = v.w;
  }
  __syncthreads();
#pragma unroll
  for (int p = 0; p < 4; ++p) {
    const int n = ry + p * 16;
    ushort4 o;
    o.x = __builtin_bit_cast(ushort, __float2bfloat16(t[cx + 0][n]));
    o.y = __builtin_bit_cast(ushort, __float2bfloat16(t[cx + 1][n]));
    o.z = __builtin_bit_cast(ushort, __float2bfloat16(t[cx + 2][n]));
    o.w = __builtin_bit_cast(ushort, __float2bfloat16(t[cx + 3][n]));
    *(ushort4*)(op + (long)(n0 + n) * ldout + k0 + cx) = o;
  }
}

// ---------------- stacked Q/K bias: [H][128] fp32 ----------------
__global__ void biasqk_kernel(const float* __restrict__ bq, const float* __restrict__ bk,
                              float* __restrict__ out) {
  const int i = blockIdx.x * 256 + threadIdx.x;
  if (i < NH * 128) {
    const int h = i >> 7, n = i & 127;
    out[i] = (n < 64) ? bq[h * 64 + n] : bk[h * 64 + n - 64];
  }
}

// ---------------- embedding + sinusoidal PE -> x fp32 + xb bf16 ----------------
__global__ __launch_bounds__(256) void embed_kernel(
    const int* __restrict__ tok, const float* __restrict__ emb,
    float* __restrict__ x, bf16* __restrict__ xb)
{
  const int gid = blockIdx.x * 256 + threadIdx.x;
  const int row = gid / (DM / 4);
  const int dc  = (gid % (DM / 4)) * 4;
  const int t = tok[row];
  const int s = row & (SQ - 1);
#pragma unroll
  for (int j = 0; j < 4; ++j) {
    const int d = dc + j;
    const float e = emb[(long)t * DM + d];
    const float div = expf(-(float)(d & ~1) * (9.210340371976184f / (float)DM));
    const float ang = (float)s * div;
    const float pe = (d & 1) ? cosf(ang) : sinf(ang);
    const float v = e + pe;
    x[(long)row * DM + d] = v;
    xb[(long)row * DM + d] = __float2bfloat16(v);
  }
}

// ---------------- masked softmax, in place over bf16 scores ----------------
__global__ __launch_bounds__(256) void softmax_kernel(
    bf16* __restrict__ P, const int* __restrict__ tok)
{
  const int row = blockIdx.x;          // (b*H+h)*S + s
  const int s = row & (SQ - 1);
  const int z = row >> 10;
  const int b = z / NH;
  bf16* sp = P + (long)row * SQ;
  const int* tb = tok + b * SQ;
  const int tid = threadIdx.x;
  const int t0 = tid * 4;

  if (tb[s] == 0) {                    // pad query: uniform attention
    const bf16 u = __float2bfloat16(1.0f / (float)SQ);
    sp[t0] = u; sp[t0 + 1] = u; sp[t0 + 2] = u; sp[t0 + 3] = u;
    return;
  }
  uint2 raw = *(const uint2*)(sp + t0);
  int4 tv = *(const int4*)(tb + t0);
  const bf16* rh = (const bf16*)&raw;
  const int tvv[4] = {tv.x, tv.y, tv.z, tv.w};
  float val[4];
  float vmax = -1e30f;
#pragma unroll
  for (int j = 0; j < 4; ++j) {
    const int t = t0 + j;
    const bool valid = (t <= s) && (tvv[j] != 0);
    val[j] = valid ? __bfloat162float(rh[j]) * 0.125f : -1e30f;
    vmax = fmaxf(vmax, val[j]);
  }
  __shared__ float red[4];
  const int lane = tid & 63, wid = tid >> 6;
  float w = vmax;
#pragma unroll
  for (int o = 32; o >= 1; o >>= 1) w = fmaxf(w, __shfl_xor(w, o));
  if (lane == 0) red[wid] = w;
  __syncthreads();
  const float Mx = fmaxf(fmaxf(red[0], red[1]), fmaxf(red[2], red[3]));
  __syncthreads();
  float e[4]; float lsum = 0.f;
#pragma unroll
  for (int j = 0; j < 4; ++j) {
    e[j] = (val[j] > -1e29f) ? expf(val[j] - Mx) : 0.f;
    lsum += e[j];
  }
  w = lsum;
#pragma unroll
  for (int o = 32; o >= 1; o >>= 1) w += __shfl_xor(w, o);
  if (lane == 0) red[wid] = w;
  __syncthreads();
  const float inv = 1.0f / (red[0] + red[1] + red[2] + red[3]);
#pragma unroll
  for (int j = 0; j < 4; ++j) sp[t0 + j] = __float2bfloat16(e[j] * inv);
}

// ---------------- residual (+head-mean) + LayerNorm, x & xb updated ----------------
template<int MODE>
__global__ __launch_bounds__(256) void ln_kernel(
    float* __restrict__ x, bf16* __restrict__ xb,
    const float* __restrict__ tmp, const bf16* __restrict__ heads,
    const float* __restrict__ g, const float* __restrict__ be)
{
  const int r = blockIdx.x;            // b*S + s
  const int b = r >> 10;
  const int s = r & (SQ - 1);
  const int tid = threadIdx.x;
  float vals[3];
  float sum = 0.f, sq = 0.f;
#pragma unroll
  for (int i = 0; i < 3; ++i) {
    const int d = tid + i * 256;
    const float a = x[(long)r * DM + d];
    float t;
    if (MODE == 0) {
      t = tmp[(long)r * DM + d];
    } else {
      float hs = 0.f;
#pragma unroll
      for (int h = 0; h < NH; ++h)
        hs += __bfloat162float(heads[((long)(b * NH + h) * SQ + s) * DM + d]);
      t = hs * (1.0f / (float)NH);
    }
    const float vv = a + t;
    vals[i] = vv;
    sum += vv; sq += vv * vv;
  }
  __shared__ float rs[4], rq[4];
  const int lane = tid & 63, wid = tid >> 6;
  float s1 = sum, s2 = sq;
#pragma unroll
  for (int o = 32; o >= 1; o >>= 1) { s1 += __shfl_xor(s1, o); s2 += __shfl_xor(s2, o); }
  if (lane == 0) { rs[wid] = s1; rq[wid] = s2; }
  __syncthreads();
  const float S1 = rs[0] + rs[1] + rs[2] + rs[3];
  const float S2 = rq[0] + rq[1] + rq[2] + rq[3];
  const float mean = S1 * (1.0f / (float)DM);
  const float var  = S2 * (1.0f / (float)DM) - mean * mean;
  const float rstd = rsqrtf(var + 1e-5f);
#pragma unroll
  for (int i = 0; i < 3; ++i) {
    const int d = tid + i * 256;
    const float o = (vals[i] - mean) * rstd * g[d] + be[d];
    x[(long)r * DM + d] = o;
    xb[(long)r * DM + d] = __float2bfloat16(o);
  }
}

extern "C" void kernel_launch(void* const* d_in, const int* in_sizes, int n_in,
                              void* d_out, int out_size, void* d_ws, size_t ws_size,
                              hipStream_t stream) {
  // ---- harness-contract tripwires ----
  const int expect_sizes[18] = {
    2048, 24576000, 3538944, 4608, 3538944, 4608, 42467328, 55296,
    4608, 4608, 4608, 4608, 14155776, 18432, 14155776, 4608, 24576000, 32000
  };
  bool sizes_ok = (n_in == 18);
  if (sizes_ok)
    for (int i = 0; i < 18; ++i) sizes_ok = sizes_ok && (in_sizes[i] == expect_sizes[i]);
  if (!sizes_ok) {
    fill_kernel<<<2048, 256, 0, stream>>>((float*)d_out, (long)out_size, 1000.0f);
    return;
  }
  if (out_size != 65536000) {
    fill_kernel<<<2048, 256, 0, stream>>>((float*)d_out, (long)out_size, 3000.0f);
    return;
  }
  if (ws_size < 158081024ull) {
    fill_kernel<<<2048, 256, 0, stream>>>((float*)d_out, (long)out_size, 2000.0f);
    return;
  }

  const int*   tok  = (const int*)d_in[0];
  const float* emb  = (const float*)d_in[1];
  const float* Wq   = (const float*)d_in[2];
  const float* bq   = (const float*)d_in[3];
  const float* Wk   = (const float*)d_in[4];
  const float* bk   = (const float*)d_in[5];
  const float* Wv   = (const float*)d_in[6];
  const float* bv   = (const float*)d_in[7];
  const float* g1   = (const float*)d_in[8];
  const float* be1  = (const float*)d_in[9];
  const float* g2   = (const float*)d_in[10];
  const float* be2  = (const float*)d_in[11];
  const float* W1   = (const float*)d_in[12];
  const float* b1   = (const float*)d_in[13];
  const float* W2   = (const float*)d_in[14];
  const float* b2   = (const float*)d_in[15];
  const float* Wout = (const float*)d_in[16];
  const float* bout = (const float*)d_in[17];

  char* ws = (char*)d_ws;
  float* x      = (float*)(ws + 0);            // fp32 [B,S,D]        6,291,456
  bf16*  xb     = (bf16*) (ws + 6291456);      // bf16 [B,S,D]        3,145,728
  bf16*  qk     = (bf16*) (ws + 9437184);      // bf16 [B,H,S,128]    6,291,456 (union w/ tmp)
  float* tmp    = (float*)(ws + 9437184);      // fp32 [B,S,D]        (FF phase)
  bf16*  vT     = (bf16*) (ws + 15728640);     // bf16 [B,H,D,S]     37,748,736
  bf16*  P      = (bf16*) (ws + 53477376);     // bf16 [B,H,S,S]     50,331,648 (union w/ ff, woutT)
  bf16*  ff     = (bf16*) (ws + 53477376);     // bf16 [B,S,FF]      12,582,912
  bf16*  woutT  = (bf16*) (ws + 53477376);     // bf16 [V,D]         49,152,000
  bf16*  heads  = (bf16*) (ws + 103809024);    // bf16 [B,H,S,D]     37,748,736
  bf16*  wqkT   = (bf16*) (ws + 141557760);    // bf16 [H,128,D]      2,359,296
  bf16*  wvT    = (bf16*) (ws + 143917056);    // bf16 [H,D,D]       14,155,776
  bf16*  w1T    = (bf16*) (ws + 141557760);    // bf16 [FF,D]         4,718,592 (FF phase)
  bf16*  w2T    = (bf16*) (ws + 146276352);    // bf16 [D,FF]         4,718,592
  float* biasqk = (float*)(ws + 158072832);    // fp32 [H,128]            6,144

  embed_kernel<<<dim3((2 * SQ * DM / 4) / 256), 256, 0, stream>>>(tok, emb, x, xb);

  for (int l = 0; l < NL; ++l) {
    // --- weight prep (attention) ---
    transpose_kernel<<<dim3(1, 12, NH), 256, 0, stream>>>(      // Wq[l,h]: [768,64] -> rows 0..63
        Wq + (long)l * NH * DM * KDH, (long)DM * KDH, KDH,
        wqkT, 128 * DM, DM);
    transpose_kernel<<<dim3(1, 12, NH), 256, 0, stream>>>(      // Wk[l,h] -> rows 64..127
        Wk + (long)l * NH * DM * KDH, (long)DM * KDH, KDH,
        wqkT + 64 * DM, 128 * DM, DM);
    transpose_kernel<<<dim3(12, 12, NH), 256, 0, stream>>>(     // Wv[l,h]: [768,768] -> T
        Wv + (long)l * NH * DM * DM, (long)DM * DM, DM,
        wvT, (long)DM * DM, DM);
    biasqk_kernel<<<6, 256, 0, stream>>>(bq + l * NH * KDH, bk + l * NH * KDH, biasqk);

    // --- fused Q|K projection: qk[b,h,s,0:64]=Q, [64:128]=K ---
    gemm_bt<true, false><<<dim3(16, 1, NH), 256, 0, stream>>>(
        2048, 128, DM, xb, 0, DM, wqkT, (long)128 * DM, DM,
        biasqk, 128,
        qk, (long)SQ * 128, (long)NH * SQ * 128, 128, 1);
    // --- V projection, written TRANSPOSED: vT[b,h,e,s] (vector ushort4 path) ---
    gemm_bt<true, false><<<dim3(16, 6, NH), 256, 0, stream>>>(
        2048, DM, DM, xb, 0, DM, wvT, (long)DM * DM, DM,
        bv + (long)l * NH * DM, DM,
        vT, (long)DM * SQ, (long)NH * DM * SQ, 1, SQ);
    // --- scores = Q @ K^T -> P ---
    gemm_bt<true, false><<<dim3(8, 8, 2 * NH), 256, 0, stream>>>(
        SQ, SQ, KDH, qk, (long)SQ * 128, 128, qk + 64, (long)SQ * 128, 128,
        (const float*)nullptr, 0,
        P, (long)SQ * SQ, 0, SQ, 1);
    softmax_kernel<<<dim3(2 * NH * SQ), 256, 0, stream>>>(P, tok);
    // --- heads = P @ V ---
    gemm_bt<true, false><<<dim3(8, 6, 2 * NH), 256, 0, stream>>>(
        SQ, DM, SQ, P, (long)SQ * SQ, SQ, vT, (long)DM * SQ, SQ,
        (const float*)nullptr, 0,
        heads, (long)SQ * DM, 0, DM, 1);
    // --- x = LN(x + mean_h(heads)) ---
    ln_kernel<1><<<dim3(2048), 256, 0, stream>>>(x, xb, nullptr, heads,
                                                 g1 + l * DM, be1 + l * DM);
    // --- weight prep (FF) ---
    transpose_kernel<<<dim3(48, 12, 1), 256, 0, stream>>>(      // W1[l]: [768,3072] -> [3072,768]
        W1 + (long)l * DM * FFD, 0, FFD, w1T, 0, DM);
    transpose_kernel<<<dim3(12, 48, 1), 256, 0, stream>>>(      // W2[l]: [3072,768] -> [768,3072]
        W2 + (long)l * FFD * DM, 0, DM, w2T, 0, FFD);
    // --- FF1: relu(x @ W1 + b1) -> ff ---
    gemm_bt<true, true><<<dim3(16, 24, 1), 256, 0, stream>>>(
        2048, FFD, DM, xb, 0, DM, w1T, 0, DM,
        b1 + (long)l * FFD, 0,
        ff, 0, (long)SQ * FFD, FFD, 1);
    // --- FF2: ff @ W2 + b2 -> tmp fp32 ---
    gemm_bt<false, false><<<dim3(16, 6, 1), 256, 0, stream>>>(
        2048, DM, FFD, ff, 0, FFD, w2T, 0, FFD,
        b2 + (long)l * DM, 0,
        tmp, 0, (long)SQ * DM, DM, 1);
    // --- x = LN(x + tmp) ---
    ln_kernel<0><<<dim3(2048), 256, 0, stream>>>(x, xb, tmp, nullptr,
                                                 g2 + l * DM, be2 + l * DM);
  }
  // --- Wout transpose (P region is dead now) + logits -> d_out fp32 ---
  transpose_kernel<<<dim3(500, 12, 1), 256, 0, stream>>>(Wout, 0, NV, woutT, 0, DM);
  gemm_bt<false, false><<<dim3(16, 250, 1), 256, 0, stream>>>(
      2048, NV, DM, xb, 0, DM, woutT, 0, DM,
      bout, 0,
      d_out, 0, (long)SQ * NV, NV, 1);
}